// Round 1
// baseline (556.288 us; speedup 1.0000x reference)
//
#include <hip/hip_runtime.h>
#include <math.h>

#define B_SZ 8192
#define IN_DIM 1024
#define K_CB 2048
#define D_SZ 256
#define BN_EPS 1e-5f

// ---------------- tiled fp32 GEMM ----------------
// C[M,N]: EPI 0: A@B ; 1: A@B + bias[col] ; 2: 2*(A@B) - h2[row] - e2[col]
// BT=false: B is [Kin,N] row-major. BT=true: B is [N,Kin] row-major (C = A@B^T).
template<int BM, int BN, int BK, bool BT, int EPI>
__global__ __launch_bounds__(256) void gemm_f32(
    const float* __restrict__ A, const float* __restrict__ Bm, float* __restrict__ C,
    int M, int N, int Kin,
    const float* __restrict__ bias, const float* __restrict__ h2v, const float* __restrict__ e2v)
{
    constexpr int TM = 4, TN = 4;
    __shared__ float As[BK][BM + 4];
    __shared__ float Bs[BK][BN + 4];
    const int tid  = threadIdx.x;
    const int row0 = blockIdx.x * BM;
    const int col0 = blockIdx.y * BN;
    const int ty = tid / (BN / TN);
    const int tx = tid % (BN / TN);
    float acc[TM][TN] = {};

    for (int k0 = 0; k0 < Kin; k0 += BK) {
        #pragma unroll
        for (int i = tid; i < BM * BK; i += 256) {
            int r = i / BK, c = i % BK;
            As[c][r] = A[(size_t)(row0 + r) * Kin + k0 + c];
        }
        if (!BT) {
            #pragma unroll
            for (int i = tid; i < BK * BN; i += 256) {
                int r = i / BN, c = i % BN;
                Bs[r][c] = Bm[(size_t)(k0 + r) * N + col0 + c];
            }
        } else {
            #pragma unroll
            for (int i = tid; i < BN * BK; i += 256) {
                int n = i / BK, c = i % BK;
                Bs[c][n] = Bm[(size_t)(col0 + n) * Kin + k0 + c];
            }
        }
        __syncthreads();
        #pragma unroll
        for (int kk = 0; kk < BK; ++kk) {
            const float4 av = *(const float4*)&As[kk][ty * TM];
            const float4 bv = *(const float4*)&Bs[kk][tx * TN];
            float a[4] = {av.x, av.y, av.z, av.w};
            float b[4] = {bv.x, bv.y, bv.z, bv.w};
            #pragma unroll
            for (int m = 0; m < TM; ++m)
                #pragma unroll
                for (int n = 0; n < TN; ++n)
                    acc[m][n] = fmaf(a[m], b[n], acc[m][n]);
        }
        __syncthreads();
    }

    #pragma unroll
    for (int m = 0; m < TM; ++m) {
        int r = row0 + ty * TM + m;
        float4 v4;
        float* vp = &v4.x;
        #pragma unroll
        for (int n = 0; n < TN; ++n) {
            int c = col0 + tx * TN + n;
            float v = acc[m][n];
            if (EPI == 1) v += bias[c];
            if (EPI == 2) v = 2.0f * v - h2v[r] - e2v[c];
            vp[n] = v;
        }
        *(float4*)&C[(size_t)r * N + col0 + tx * TN] = v4;
    }
}

// ---------------- BN batch stats (two-stage, deterministic) ----------------
__global__ __launch_bounds__(256) void bn_partial(const float* __restrict__ h, float* __restrict__ part)
{
    const int d = threadIdx.x;              // 256 columns
    const int blk = blockIdx.x;             // 128 blocks x 64 rows
    const int r0 = blk * (B_SZ / 128);
    float s = 0.f, sq = 0.f;
    for (int r = r0; r < r0 + (B_SZ / 128); ++r) {
        float v = h[(size_t)r * D_SZ + d];
        s += v; sq += v * v;
    }
    part[blk * 512 + d]       = s;
    part[blk * 512 + 256 + d] = sq;
}

__global__ __launch_bounds__(256) void bn_finalize(
    const float* __restrict__ part, const float* __restrict__ gamma, const float* __restrict__ beta,
    float* __restrict__ scale, float* __restrict__ shift)
{
    const int d = threadIdx.x;
    float s = 0.f, sq = 0.f;
    for (int b = 0; b < 128; ++b) { s += part[b * 512 + d]; sq += part[b * 512 + 256 + d]; }
    float mu  = s / (float)B_SZ;
    float var = sq / (float)B_SZ - mu * mu;
    float sc  = gamma[d] * rsqrtf(var + BN_EPS);
    scale[d] = sc;
    shift[d] = beta[d] - mu * sc;
}

// ---------------- normalize h in-place + row sum of squares ----------------
__global__ __launch_bounds__(256) void norm_h2(
    float* __restrict__ h, const float* __restrict__ scale, const float* __restrict__ shift,
    float* __restrict__ h2out)
{
    const int wave = threadIdx.x >> 6, lane = threadIdx.x & 63;
    const int row = blockIdx.x * 4 + wave;
    float4* h4 = (float4*)(h + (size_t)row * D_SZ);
    const float4 sc = ((const float4*)scale)[lane];
    const float4 sh = ((const float4*)shift)[lane];
    float4 v = h4[lane];
    v.x = fmaf(v.x, sc.x, sh.x);
    v.y = fmaf(v.y, sc.y, sh.y);
    v.z = fmaf(v.z, sc.z, sh.z);
    v.w = fmaf(v.w, sc.w, sh.w);
    h4[lane] = v;
    float ss = v.x * v.x + v.y * v.y + v.z * v.z + v.w * v.w;
    #pragma unroll
    for (int off = 32; off > 0; off >>= 1) ss += __shfl_down(ss, off);
    if (lane == 0) h2out[row] = ss;
}

// ---------------- codebook row norms ----------------
__global__ __launch_bounds__(256) void e2_kernel(const float* __restrict__ E, float* __restrict__ e2)
{
    const int wave = threadIdx.x >> 6, lane = threadIdx.x & 63;
    const int row = blockIdx.x * 4 + wave;
    const float4 v = ((const float4*)(E + (size_t)row * D_SZ))[lane];
    float ss = v.x * v.x + v.y * v.y + v.z * v.z + v.w * v.w;
    #pragma unroll
    for (int off = 32; off > 0; off >>= 1) ss += __shfl_down(ss, off);
    if (lane == 0) e2[row] = ss;
}

// ---------------- dual row softmax: probs (no noise) + assignments (gumbel) ----------------
__global__ __launch_bounds__(256) void softmax_dual(
    const float* __restrict__ logits, const float* __restrict__ u,
    float* __restrict__ probs, float* __restrict__ assign)
{
    const int row = blockIdx.x;
    const int tid = threadIdx.x;
    const int wave = tid >> 6, lane = tid & 63;
    __shared__ float red[2][4];

    const float4* L4 = (const float4*)(logits + (size_t)row * K_CB);
    const float4* U4 = (const float4*)(u + (size_t)row * K_CB);
    float4 la = L4[tid * 2], lb = L4[tid * 2 + 1];
    float4 ua = U4[tid * 2], ub = U4[tid * 2 + 1];
    float l[8]  = {la.x, la.y, la.z, la.w, lb.x, lb.y, lb.z, lb.w};
    float uu[8] = {ua.x, ua.y, ua.z, ua.w, ub.x, ub.y, ub.z, ub.w};
    float s2[8];
    float m1 = -1e30f, m2 = -1e30f;
    #pragma unroll
    for (int j = 0; j < 8; ++j) {
        float g = -logf(-logf(uu[j] + 1e-10f) + 1e-10f);
        s2[j] = l[j] + g;                    // TAU = 1
        m1 = fmaxf(m1, l[j]);
        m2 = fmaxf(m2, s2[j]);
    }
    #pragma unroll
    for (int off = 32; off > 0; off >>= 1) {
        m1 = fmaxf(m1, __shfl_down(m1, off));
        m2 = fmaxf(m2, __shfl_down(m2, off));
    }
    if (lane == 0) { red[0][wave] = m1; red[1][wave] = m2; }
    __syncthreads();
    m1 = fmaxf(fmaxf(red[0][0], red[0][1]), fmaxf(red[0][2], red[0][3]));
    m2 = fmaxf(fmaxf(red[1][0], red[1][1]), fmaxf(red[1][2], red[1][3]));
    __syncthreads();

    float p1[8], p2[8];
    float sum1 = 0.f, sum2 = 0.f;
    #pragma unroll
    for (int j = 0; j < 8; ++j) {
        p1[j] = expf(l[j]  - m1); sum1 += p1[j];
        p2[j] = expf(s2[j] - m2); sum2 += p2[j];
    }
    #pragma unroll
    for (int off = 32; off > 0; off >>= 1) {
        sum1 += __shfl_down(sum1, off);
        sum2 += __shfl_down(sum2, off);
    }
    if (lane == 0) { red[0][wave] = sum1; red[1][wave] = sum2; }
    __syncthreads();
    const float r1 = 1.f / (red[0][0] + red[0][1] + red[0][2] + red[0][3]);
    const float r2 = 1.f / (red[1][0] + red[1][1] + red[1][2] + red[1][3]);

    float4* P4 = (float4*)(probs  + (size_t)row * K_CB);
    float4* A4 = (float4*)(assign + (size_t)row * K_CB);
    float4 o;
    o = make_float4(p1[0] * r1, p1[1] * r1, p1[2] * r1, p1[3] * r1); P4[tid * 2]     = o;
    o = make_float4(p1[4] * r1, p1[5] * r1, p1[6] * r1, p1[7] * r1); P4[tid * 2 + 1] = o;
    o = make_float4(p2[0] * r2, p2[1] * r2, p2[2] * r2, p2[3] * r2); A4[tid * 2]     = o;
    o = make_float4(p2[4] * r2, p2[5] * r2, p2[6] * r2, p2[7] * r2); A4[tid * 2 + 1] = o;
}

extern "C" void kernel_launch(void* const* d_in, const int* in_sizes, int n_in,
                              void* d_out, int out_size, void* d_ws, size_t ws_size,
                              hipStream_t stream)
{
    const float* x     = (const float*)d_in[0];
    const float* u     = (const float*)d_in[1];
    const float* W     = (const float*)d_in[2];
    const float* bias  = (const float*)d_in[3];
    const float* gamma = (const float*)d_in[4];
    const float* beta  = (const float*)d_in[5];
    const float* E     = (const float*)d_in[6];

    float* probs = (float*)d_out;                       // [B, K]
    float* z     = probs + (size_t)B_SZ * K_CB;         // [B, D]

    float* ws     = (float*)d_ws;
    float* h      = ws;                                  // B*D
    float* logits = h + (size_t)B_SZ * D_SZ;             // B*K (reused for assignments)
    float* part   = logits + (size_t)B_SZ * K_CB;        // 128*512
    float* scale  = part + 128 * 512;                    // D
    float* shift  = scale + D_SZ;                        // D
    float* h2     = shift + D_SZ;                        // B
    float* e2     = h2 + B_SZ;                           // K

    // 1) h = x @ W + b
    {
        dim3 g(B_SZ / 64, D_SZ / 64);
        gemm_f32<64, 64, 32, false, 1><<<g, 256, 0, stream>>>(
            x, W, h, B_SZ, D_SZ, IN_DIM, bias, nullptr, nullptr);
    }
    // 2) batch-norm stats -> scale/shift
    bn_partial<<<128, 256, 0, stream>>>(h, part);
    bn_finalize<<<1, 256, 0, stream>>>(part, gamma, beta, scale, shift);
    // 3) normalize h in place, row sums of squares
    norm_h2<<<B_SZ / 4, 256, 0, stream>>>(h, scale, shift, h2);
    // 4) codebook norms
    e2_kernel<<<K_CB / 4, 256, 0, stream>>>(E, e2);
    // 5) logits = 2*(h @ E^T) - h2[row] - e2[col]
    {
        dim3 g(B_SZ / 64, K_CB / 64);
        gemm_f32<64, 64, 32, true, 2><<<g, 256, 0, stream>>>(
            h, E, logits, B_SZ, K_CB, D_SZ, nullptr, h2, e2);
    }
    // 6) probs -> d_out ; assignments -> overwrite logits
    softmax_dual<<<B_SZ, 256, 0, stream>>>(logits, u, probs, logits);
    // 7) z = assignments @ E
    {
        dim3 g(B_SZ / 64, D_SZ / 64);
        gemm_f32<64, 64, 32, false, 0><<<g, 256, 0, stream>>>(
            logits, E, z, B_SZ, D_SZ, K_CB, nullptr, nullptr, nullptr);
    }
}

// Round 3
// 125.034 us; speedup vs baseline: 4.4491x; 4.4491x over previous
//
#include <hip/hip_runtime.h>
#include <math.h>

#define B_SZ 8192
#define IN_DIM 1024
#define K_CB 2048
#define D_SZ 256
#define BN_EPS 1e-5f

typedef _Float16 f16;
typedef _Float16 f16x8 __attribute__((ext_vector_type(8)));
typedef _Float16 f16x4 __attribute__((ext_vector_type(4)));
typedef float    f32x4 __attribute__((ext_vector_type(4)));

#define GLOAD_LDS16(g, l) __builtin_amdgcn_global_load_lds(                      \
    (const __attribute__((address_space(1))) unsigned int*)(g),                  \
    (__attribute__((address_space(3))) unsigned int*)(l), 16, 0, 0)

// ---------------------------------------------------------------------------
// f16 MFMA GEMM: C[M,N] = A[M,K] @ B[N,K]^T   (both operands K-contiguous)
// EPI 0: write f32 C           (z = assign @ E^T  via ET)
// EPI 1: write f16 C + bias    (h = x @ W^T  via WT; A is f32, reg-converted)
// EPI 2: write f32 2*C - h2[r] - e2[c]   (logits)
// LDS: [rows][BK] f16, 16B granules XOR-swizzled by (row & (G-1)).
// ---------------------------------------------------------------------------
template<int BM, int BN, int BK, int EPI, bool A32>
__global__ __launch_bounds__(256) void gemm_mfma(
    const void* __restrict__ Aptr, int lda,
    const f16* __restrict__ Bptr, int ldb,
    void* __restrict__ Cptr, int ldc, int Kdim,
    const float* __restrict__ bias, const float* __restrict__ h2v,
    const float* __restrict__ e2v)
{
    constexpr int G    = BK / 8;      // 16B granules per LDS row
    constexpr int MASK = G - 1;
    constexpr int WM = BM / 2, WN = BN / 2;     // 2x2 waves
    constexpr int FM = WM / 16, FN = WN / 16;
    constexpr int CH_A = BM * G;      // 16B chunks in A tile
    constexpr int CH_B = BN * G;

    __shared__ char lds[(BM + BN) * BK * 2];
    char* As = lds;
    char* Bs = lds + BM * BK * 2;

    const int tid  = threadIdx.x;
    const int w    = tid >> 6, lane = tid & 63;
    const int wm   = w >> 1,   wn   = w & 1;
    const int row0 = blockIdx.x * BM;
    const int col0 = blockIdx.y * BN;

    f32x4 acc[FM][FN] = {};

    for (int k0 = 0; k0 < Kdim; k0 += BK) {
        // ---- stage B (f16 global -> LDS, linear dest, pre-swizzled source)
        #pragma unroll
        for (int i = 0; i < CH_B / 256; ++i) {
            const int base = (i * 4 + w) * 64;
            const int s = base + lane;
            const int r = s / G, c = s % G;
            const f16* src = Bptr + (size_t)(col0 + r) * ldb + k0 + ((c ^ (r & MASK)) * 8);
            GLOAD_LDS16(src, Bs + base * 16);
        }
        // ---- stage A
        if (!A32) {
            #pragma unroll
            for (int i = 0; i < CH_A / 256; ++i) {
                const int base = (i * 4 + w) * 64;
                const int s = base + lane;
                const int r = s / G, c = s % G;
                const f16* src = (const f16*)Aptr + (size_t)(row0 + r) * lda + k0 + ((c ^ (r & MASK)) * 8);
                GLOAD_LDS16(src, As + base * 16);
            }
        } else {
            // f32 global -> convert -> swizzled ds_write
            #pragma unroll
            for (int i = 0; i < CH_A / 256; ++i) {
                const int s = i * 256 + tid;
                const int r = s / G, c = s % G;
                const float* src = (const float*)Aptr + (size_t)(row0 + r) * lda + k0 + c * 8;
                const float4 v0 = ((const float4*)src)[0];
                const float4 v1 = ((const float4*)src)[1];
                f16x8 d;
                d[0] = (f16)v0.x; d[1] = (f16)v0.y; d[2] = (f16)v0.z; d[3] = (f16)v0.w;
                d[4] = (f16)v1.x; d[5] = (f16)v1.y; d[6] = (f16)v1.z; d[7] = (f16)v1.w;
                *(f16x8*)(As + (r * G + (c ^ (r & MASK))) * 16) = d;
            }
        }
        __syncthreads();

        // ---- MFMA inner loop
        #pragma unroll
        for (int kk = 0; kk < BK / 32; ++kk) {
            f16x8 af[FM], bf[FN];
            #pragma unroll
            for (int m = 0; m < FM; ++m) {
                const int r = wm * WM + m * 16 + (lane & 15);
                const int g = (kk * 4 + (lane >> 4)) ^ (r & MASK);
                af[m] = *(const f16x8*)(As + r * (BK * 2) + g * 16);
            }
            #pragma unroll
            for (int n = 0; n < FN; ++n) {
                const int r = wn * WN + n * 16 + (lane & 15);
                const int g = (kk * 4 + (lane >> 4)) ^ (r & MASK);
                bf[n] = *(const f16x8*)(Bs + r * (BK * 2) + g * 16);
            }
            #pragma unroll
            for (int m = 0; m < FM; ++m)
                #pragma unroll
                for (int n = 0; n < FN; ++n)
                    acc[m][n] = __builtin_amdgcn_mfma_f32_16x16x32_f16(af[m], bf[n], acc[m][n], 0, 0, 0);
        }
        __syncthreads();
    }

    // ---- epilogue: C/D layout col = lane&15, row = (lane>>4)*4 + j
    #pragma unroll
    for (int m = 0; m < FM; ++m) {
        const int rbase = row0 + wm * WM + m * 16 + (lane >> 4) * 4;
        #pragma unroll
        for (int n = 0; n < FN; ++n) {
            const int c = col0 + wn * WN + n * 16 + (lane & 15);
            #pragma unroll
            for (int j = 0; j < 4; ++j) {
                const float v = acc[m][n][j];
                if (EPI == 0) {
                    ((float*)Cptr)[(size_t)(rbase + j) * ldc + c] = v;
                } else if (EPI == 1) {
                    ((f16*)Cptr)[(size_t)(rbase + j) * ldc + c] = (f16)(v + bias[c]);
                } else {
                    ((float*)Cptr)[(size_t)(rbase + j) * ldc + c] =
                        2.0f * v - h2v[rbase + j] - e2v[c];
                }
            }
        }
    }
}

// ---------------- conversions ----------------
__global__ __launch_bounds__(256) void conv_WT(const float* __restrict__ W, f16* __restrict__ WT)
{   // W [1024][256] -> WT [256][1024]
    const int r = blockIdx.x, c = threadIdx.x;
    WT[c * 1024 + r] = (f16)W[r * 256 + c];
}

__global__ __launch_bounds__(256) void conv_E(const float* __restrict__ E,
                                              f16* __restrict__ E16, f16* __restrict__ ET)
{   // E [2048][256] -> E16 same, ET [256][2048]
    const int r = blockIdx.x, c = threadIdx.x;
    const float v = E[r * 256 + c];
    E16[r * 256 + c] = (f16)v;
    ET[c * 2048 + r] = (f16)v;
}

// ---------------- BN batch stats (two-stage, deterministic) ----------------
__global__ __launch_bounds__(256) void bn_partial(const f16* __restrict__ h16, float* __restrict__ part)
{
    const int d = threadIdx.x;
    const int blk = blockIdx.x;                 // 128 blocks x 64 rows
    const int r0 = blk * (B_SZ / 128);
    float s = 0.f, sq = 0.f;
    for (int r = r0; r < r0 + (B_SZ / 128); ++r) {
        const float v = (float)h16[(size_t)r * D_SZ + d];
        s += v; sq += v * v;
    }
    part[blk * 512 + d]       = s;
    part[blk * 512 + 256 + d] = sq;
}

__global__ __launch_bounds__(256) void bn_finalize(
    const float* __restrict__ part, const float* __restrict__ gamma, const float* __restrict__ beta,
    float* __restrict__ scale, float* __restrict__ shift)
{
    const int d = threadIdx.x;
    float s = 0.f, sq = 0.f;
    for (int b = 0; b < 128; ++b) { s += part[b * 512 + d]; sq += part[b * 512 + 256 + d]; }
    const float mu  = s / (float)B_SZ;
    const float var = sq / (float)B_SZ - mu * mu;
    const float sc  = gamma[d] * rsqrtf(var + BN_EPS);
    scale[d] = sc;
    shift[d] = beta[d] - mu * sc;
}

// ---------------- normalize h16 in place + row sum of squares ----------------
__global__ __launch_bounds__(256) void norm_h2(
    f16* __restrict__ h16, const float* __restrict__ scale, const float* __restrict__ shift,
    float* __restrict__ h2out)
{
    const int wave = threadIdx.x >> 6, lane = threadIdx.x & 63;
    const int row = blockIdx.x * 4 + wave;
    f16x4* hp = (f16x4*)(h16 + (size_t)row * D_SZ);
    f16x4 v = hp[lane];
    const float4 sc = ((const float4*)scale)[lane];
    const float4 sh = ((const float4*)shift)[lane];
    const float f0 = fmaf((float)v[0], sc.x, sh.x);
    const float f1 = fmaf((float)v[1], sc.y, sh.y);
    const float f2 = fmaf((float)v[2], sc.z, sh.z);
    const float f3 = fmaf((float)v[3], sc.w, sh.w);
    v[0] = (f16)f0; v[1] = (f16)f1; v[2] = (f16)f2; v[3] = (f16)f3;
    hp[lane] = v;
    float ss = f0 * f0 + f1 * f1 + f2 * f2 + f3 * f3;
    #pragma unroll
    for (int off = 32; off > 0; off >>= 1) ss += __shfl_down(ss, off);
    if (lane == 0) h2out[row] = ss;
}

// ---------------- codebook row norms (from f32 E) ----------------
__global__ __launch_bounds__(256) void e2_kernel(const float* __restrict__ E, float* __restrict__ e2)
{
    const int wave = threadIdx.x >> 6, lane = threadIdx.x & 63;
    const int row = blockIdx.x * 4 + wave;
    const float4 v = ((const float4*)(E + (size_t)row * D_SZ))[lane];
    float ss = v.x * v.x + v.y * v.y + v.z * v.z + v.w * v.w;
    #pragma unroll
    for (int off = 32; off > 0; off >>= 1) ss += __shfl_down(ss, off);
    if (lane == 0) e2[row] = ss;
}

// ---------------- dual row softmax: probs f32 + assignments f16 ----------------
__global__ __launch_bounds__(256) void softmax_dual(
    const float* __restrict__ logits, const float* __restrict__ u,
    float* __restrict__ probs, f16* __restrict__ assign16)
{
    const int row = blockIdx.x;
    const int tid = threadIdx.x;
    const int wave = tid >> 6, lane = tid & 63;
    __shared__ float red[2][4];

    const float4* L4 = (const float4*)(logits + (size_t)row * K_CB);
    const float4* U4 = (const float4*)(u + (size_t)row * K_CB);
    const float4 la = L4[tid * 2], lb = L4[tid * 2 + 1];
    const float4 ua = U4[tid * 2], ub = U4[tid * 2 + 1];
    float l[8]  = {la.x, la.y, la.z, la.w, lb.x, lb.y, lb.z, lb.w};
    float uu[8] = {ua.x, ua.y, ua.z, ua.w, ub.x, ub.y, ub.z, ub.w};
    float s2[8];
    float m1 = -1e30f, m2 = -1e30f;
    #pragma unroll
    for (int j = 0; j < 8; ++j) {
        const float g = -logf(-logf(uu[j] + 1e-10f) + 1e-10f);
        s2[j] = l[j] + g;                    // TAU = 1
        m1 = fmaxf(m1, l[j]);
        m2 = fmaxf(m2, s2[j]);
    }
    #pragma unroll
    for (int off = 32; off > 0; off >>= 1) {
        m1 = fmaxf(m1, __shfl_down(m1, off));
        m2 = fmaxf(m2, __shfl_down(m2, off));
    }
    if (lane == 0) { red[0][wave] = m1; red[1][wave] = m2; }
    __syncthreads();
    m1 = fmaxf(fmaxf(red[0][0], red[0][1]), fmaxf(red[0][2], red[0][3]));
    m2 = fmaxf(fmaxf(red[1][0], red[1][1]), fmaxf(red[1][2], red[1][3]));
    __syncthreads();

    float p1[8], p2[8];
    float sum1 = 0.f, sum2 = 0.f;
    #pragma unroll
    for (int j = 0; j < 8; ++j) {
        p1[j] = expf(l[j]  - m1); sum1 += p1[j];
        p2[j] = expf(s2[j] - m2); sum2 += p2[j];
    }
    #pragma unroll
    for (int off = 32; off > 0; off >>= 1) {
        sum1 += __shfl_down(sum1, off);
        sum2 += __shfl_down(sum2, off);
    }
    if (lane == 0) { red[0][wave] = sum1; red[1][wave] = sum2; }
    __syncthreads();
    const float r1 = 1.f / (red[0][0] + red[0][1] + red[0][2] + red[0][3]);
    const float r2 = 1.f / (red[1][0] + red[1][1] + red[1][2] + red[1][3]);

    float4* P4 = (float4*)(probs + (size_t)row * K_CB);
    float4 o;
    o = make_float4(p1[0] * r1, p1[1] * r1, p1[2] * r1, p1[3] * r1); P4[tid * 2]     = o;
    o = make_float4(p1[4] * r1, p1[5] * r1, p1[6] * r1, p1[7] * r1); P4[tid * 2 + 1] = o;

    // assignments in f16, aliased into this row's own logits storage (stride 4096 f16)
    f16* A16 = assign16 + (size_t)row * 4096;
    f16x8 a8;
    #pragma unroll
    for (int j = 0; j < 8; ++j) a8[j] = (f16)(p2[j] * r2);
    *(f16x8*)(A16 + tid * 8) = a8;
}

extern "C" void kernel_launch(void* const* d_in, const int* in_sizes, int n_in,
                              void* d_out, int out_size, void* d_ws, size_t ws_size,
                              hipStream_t stream)
{
    const float* x     = (const float*)d_in[0];
    const float* u     = (const float*)d_in[1];
    const float* W     = (const float*)d_in[2];
    const float* bias  = (const float*)d_in[3];
    const float* gamma = (const float*)d_in[4];
    const float* beta  = (const float*)d_in[5];
    const float* E     = (const float*)d_in[6];

    float* probs = (float*)d_out;                       // [B, K] f32
    float* z     = probs + (size_t)B_SZ * K_CB;         // [B, D] f32

    char* ws = (char*)d_ws;
    float* logits = (float*)ws;                                   // B*K f32 (64MB)
    ws += (size_t)B_SZ * K_CB * 4;
    f16* h16 = (f16*)ws;      ws += (size_t)B_SZ * D_SZ * 2;      // 4MB
    f16* WT16 = (f16*)ws;     ws += (size_t)D_SZ * IN_DIM * 2;    // 0.5MB
    f16* E16 = (f16*)ws;      ws += (size_t)K_CB * D_SZ * 2;      // 1MB
    f16* ET16 = (f16*)ws;     ws += (size_t)D_SZ * K_CB * 2;      // 1MB
    float* part = (float*)ws; ws += 128 * 512 * 4;
    float* scale = (float*)ws; ws += D_SZ * 4;
    float* shift = (float*)ws; ws += D_SZ * 4;
    float* h2 = (float*)ws;   ws += B_SZ * 4;
    float* e2 = (float*)ws;   ws += K_CB * 4;
    f16* assign16 = (f16*)logits;                                 // aliased (stride 4096)

    // prep: transposed f16 operands + codebook norms
    conv_WT<<<IN_DIM, 256, 0, stream>>>(W, WT16);
    conv_E<<<K_CB, 256, 0, stream>>>(E, E16, ET16);
    e2_kernel<<<K_CB / 4, 256, 0, stream>>>(E, e2);

    // 1) h16 = f16(x @ W + b)            M=8192 N=256 K=1024
    {
        dim3 g(B_SZ / 64, D_SZ / 64);
        gemm_mfma<64, 64, 64, 1, true><<<g, 256, 0, stream>>>(
            x, IN_DIM, WT16, IN_DIM, h16, D_SZ, IN_DIM, bias, nullptr, nullptr);
    }
    // 2) BN stats -> scale/shift; 3) normalize + h2
    bn_partial<<<128, 256, 0, stream>>>(h16, part);
    bn_finalize<<<1, 256, 0, stream>>>(part, gamma, beta, scale, shift);
    norm_h2<<<B_SZ / 4, 256, 0, stream>>>(h16, scale, shift, h2);

    // 5) logits = 2*(h @ E^T) - h2 - e2   M=8192 N=2048 K=256
    {
        dim3 g(B_SZ / 128, K_CB / 128);
        gemm_mfma<128, 128, 64, 2, false><<<g, 256, 0, stream>>>(
            h16, D_SZ, E16, D_SZ, logits, K_CB, D_SZ, nullptr, h2, e2);
    }
    // 6) probs -> d_out ; assignments f16 -> aliased over logits
    softmax_dual<<<B_SZ, 256, 0, stream>>>(logits, u, probs, assign16);

    // 7) z = assign @ E                   M=8192 N=256 K=2048 (B = ET16 [256][2048], ldb = K_CB)
    {
        dim3 g(B_SZ / 64, D_SZ / 64);
        gemm_mfma<64, 64, 128, 0, false><<<g, 256, 0, stream>>>(
            assign16, 4096, ET16, K_CB, z, D_SZ, K_CB, nullptr, nullptr, nullptr);
    }
}